// Round 1
// baseline (328.426 us; speedup 1.0000x reference)
//
#include <hip/hip_runtime.h>

// GRU: B=8192, T=1024, I=3, H=4, fp32.
// R4: dual-chain ILP. 256 blocks x 128 threads (2 waves), 32 batches/block.
//   wave 0 (recurrence): 16 quads; quad qd owns batches A=qd, B=qd+16.
//     Lane (qd,j) runs TWO independent h-chains (hA,hB) -> chain B's ops
//     fill chain A's exp2/rcp dependency stalls (was 29% VALUBusy, 70% stall).
//     Gate args as fused 4-fma chains (sr/sz/bhn as leaf).
//   wave 1 (helper): gi = x*w_ih^T + b for 32 batches, TC=8 steps/chunk,
//     double-buffered; flushes out. gi batch-stride 5 (coprime to 32) ->
//     helper ds_writes conflict-free (old layout was 8-way conflicted).
// Weights pre-scaled (-log2e for r,z; 2log2e for n) => act = rcp(1+exp2(a)).

#define TC 8            // timesteps per chunk (128 chunks)
#define GI_T 480        // gi stride per t: 3 gates * 160
#define GI_G 160        // gi stride per gate: 32 batches * 5
#define OS_T 132        // out_s stride per t: 32 batches * 4 + 4 pad

template<int CTRL>
__device__ __forceinline__ float dpp_rot(float v) {
    int i = __builtin_bit_cast(int, v);
    int r = __builtin_amdgcn_mov_dpp(i, CTRL, 0xf, 0xf, true);
    return __builtin_bit_cast(float, r);
}
__device__ __forceinline__ float vrcp(float x)  { return __builtin_amdgcn_rcpf(x); }
__device__ __forceinline__ float vexp2(float x) { return __builtin_amdgcn_exp2f(x); }

__global__ __launch_bounds__(128) void gru_kernel(
    const float* __restrict__ x,     // [B, T, 3]
    const float* __restrict__ w_ih,  // [12, 3]
    const float* __restrict__ w_hh,  // [12, 4]
    const float* __restrict__ b_ih,  // [12]
    const float* __restrict__ b_hh,  // [12]
    float* __restrict__ out)         // [B*T*4] then h_n [B*4]
{
    __shared__ float gi_s[2][TC * GI_T];                 // 30.0 KB
    __shared__ __align__(16) float out_s[2][TC * OS_T];  //  8.25 KB

    const int tid = threadIdx.x;
    const int b0  = blockIdx.x * 32;

    const float NL2E = -1.4426950408889634f;  // -log2(e)
    const float P2   =  2.8853900817779268f;  //  2*log2(e)

    if (tid < 64) {
        // ================= recurrence wave =================
        const int qd = tid >> 2;  // quad 0..15: batches A=qd, B=qd+16
        const int j  = tid & 3;   // hidden unit

        // w_hh rows permuted so index m multiplies h_{(j+m)&3} (DPP order)
        float whr[4], whz[4], whn[4];
        #pragma unroll
        for (int m = 0; m < 4; ++m) {
            int k = (j + m) & 3;
            whr[m] = NL2E * w_hh[j * 4 + k];
            whz[m] = NL2E * w_hh[(4 + j) * 4 + k];
            whn[m] = P2   * w_hh[(8 + j) * 4 + k];
        }
        const float bhn = P2 * b_hh[8 + j];

        float hA = 0.0f, hB = 0.0f;
        __syncthreads();   // gi chunk 0 ready

        for (int c = 0; c < 128; ++c) {
            const float* g = &gi_s[c & 1][qd * 5 + j];
            float*      os = &out_s[c & 1][(qd << 2) + j];

            // stage the chunk's gi into regs (bulk ds_reads, off the h-chain)
            float srA[TC], szA[TC], snA[TC], srB[TC], szB[TC], snB[TC];
            #pragma unroll
            for (int t = 0; t < TC; ++t) {
                const float* gt = g + t * GI_T;
                srA[t] = gt[0];          srB[t] = gt[80];
                szA[t] = gt[GI_G];       szB[t] = gt[GI_G + 80];
                snA[t] = gt[2 * GI_G];   snB[t] = gt[2 * GI_G + 80];
            }

            #pragma unroll
            for (int t = 0; t < TC; ++t) {
                float hA1 = dpp_rot<0x39>(hA);
                float hA2 = dpp_rot<0x4E>(hA);
                float hA3 = dpp_rot<0x93>(hA);
                float hB1 = dpp_rot<0x39>(hB);
                float hB2 = dpp_rot<0x4E>(hB);
                float hB3 = dpp_rot<0x93>(hB);

                // fused 4-fma chains, leaf = staged gi (or bhn for n-gate)
                float aRA = fmaf(whr[3], hA3, fmaf(whr[2], hA2, fmaf(whr[1], hA1, fmaf(whr[0], hA, srA[t]))));
                float aRB = fmaf(whr[3], hB3, fmaf(whr[2], hB2, fmaf(whr[1], hB1, fmaf(whr[0], hB, srB[t]))));
                float aZA = fmaf(whz[3], hA3, fmaf(whz[2], hA2, fmaf(whz[1], hA1, fmaf(whz[0], hA, szA[t]))));
                float aZB = fmaf(whz[3], hB3, fmaf(whz[2], hB2, fmaf(whz[1], hB1, fmaf(whz[0], hB, szB[t]))));
                float gNA = fmaf(whn[3], hA3, fmaf(whn[2], hA2, fmaf(whn[1], hA1, fmaf(whn[0], hA, bhn))));
                float gNB = fmaf(whn[3], hB3, fmaf(whn[2], hB2, fmaf(whn[1], hB1, fmaf(whn[0], hB, bhn))));

                float rA = vrcp(1.0f + vexp2(aRA));   // sigmoid (pre-scaled)
                float rB = vrcp(1.0f + vexp2(aRB));
                float zA = vrcp(1.0f + vexp2(aZA));
                float zB = vrcp(1.0f + vexp2(aZB));

                // off-chain epilogue prep (only one fma follows the final rcp)
                float omzA = 1.0f - zA,            omzB = 1.0f - zB;
                float szhA = fmaf(zA, hA, omzA),   szhB = fmaf(zB, hB, omzB);
                float m2A  = -2.0f * omzA,         m2B  = -2.0f * omzB;

                // n-path: u = 1/(1+e^{2a}); h' = omz*(1-2u)+z*h
                float uA = vrcp(1.0f + vexp2(fmaf(rA, gNA, snA[t])));
                float uB = vrcp(1.0f + vexp2(fmaf(rB, gNB, snB[t])));
                hA = fmaf(m2A, uA, szhA);
                hB = fmaf(m2B, uB, szhB);

                os[t * OS_T]      = hA;   // batch qd
                os[t * OS_T + 64] = hB;   // batch qd+16
            }
            __syncthreads();
        }
        // h_n tail
        out[33554432LL + (long long)(b0 + qd) * 4 + j]      = hA;
        out[33554432LL + (long long)(b0 + 16 + qd) * 4 + j] = hB;

    } else {
        // ================= helper wave =================
        const int hl = tid - 64;
        const int bb = hl >> 1;   // batch slot 0..31
        const int s  = hl & 1;    // t-slice 0..1

        // all 12 w_ih rows + fused biases (wave-uniform -> scalar regs)
        float wr[4][3], wz[4][3], wn[4][3];
        float cbr[4], cbz[4], cbn[4];
        #pragma unroll
        for (int jj = 0; jj < 4; ++jj) {
            #pragma unroll
            for (int k = 0; k < 3; ++k) {
                wr[jj][k] = NL2E * w_ih[jj * 3 + k];
                wz[jj][k] = NL2E * w_ih[(4 + jj) * 3 + k];
                wn[jj][k] = P2   * w_ih[(8 + jj) * 3 + k];
            }
            cbr[jj] = NL2E * (b_ih[jj]     + b_hh[jj]);
            cbz[jj] = NL2E * (b_ih[4 + jj] + b_hh[4 + jj]);
            cbn[jj] = P2   * b_ih[8 + jj];
        }

        const long long xbase = (long long)(b0 + bb) * 3072;

        // gi compute for chunk cc into buf
        auto compute_gi = [&](int cc, float* buf) {
            #pragma unroll
            for (int k = 0; k < 4; ++k) {
                int tl = k * 2 + s;                       // 0..7
                const float* xp = x + xbase + (long long)(cc * TC + tl) * 3;
                float x0 = xp[0], x1 = xp[1], x2 = xp[2];
                float* gp = &buf[tl * GI_T + bb * 5];
                #pragma unroll
                for (int jj = 0; jj < 4; ++jj) {
                    gp[jj]             = fmaf(wr[jj][0], x0, fmaf(wr[jj][1], x1, fmaf(wr[jj][2], x2, cbr[jj])));
                    gp[GI_G + jj]      = fmaf(wz[jj][0], x0, fmaf(wz[jj][1], x1, fmaf(wz[jj][2], x2, cbz[jj])));
                    gp[2 * GI_G + jj]  = fmaf(wn[jj][0], x0, fmaf(wn[jj][1], x1, fmaf(wn[jj][2], x2, cbn[jj])));
                }
            }
        };
        // flush chunk cc from buf to global (32 floats per batch row)
        auto flush_out = [&](int cc, const float* buf) {
            #pragma unroll
            for (int u = 0; u < 4; ++u) {
                int f  = u * 64 + hl;     // 0..255 cells
                int fb = f >> 3;          // batch 0..31
                int ft = f & 7;           // t 0..7
                float4 v = *(const float4*)&buf[ft * OS_T + fb * 4];
                *(float4*)(out + (long long)(b0 + fb) * 4096 + (long long)(cc * TC + ft) * 4) = v;
            }
        };

        compute_gi(0, gi_s[0]);
        __syncthreads();   // release chunk 0

        for (int c = 0; c < 128; ++c) {
            if (c < 127) compute_gi(c + 1, gi_s[(c + 1) & 1]);
            if (c > 0)   flush_out(c - 1, out_s[(c - 1) & 1]);
            __syncthreads();
        }
        flush_out(127, out_s[1]);
    }
}

extern "C" void kernel_launch(void* const* d_in, const int* in_sizes, int n_in,
                              void* d_out, int out_size, void* d_ws, size_t ws_size,
                              hipStream_t stream) {
    const float* x    = (const float*)d_in[0];
    const float* w_ih = (const float*)d_in[1];
    const float* w_hh = (const float*)d_in[2];
    const float* b_ih = (const float*)d_in[3];
    const float* b_hh = (const float*)d_in[4];
    float* out = (float*)d_out;

    dim3 grid(256), block(128);   // 256 blocks x 32 batches = 8192; 2 waves/block
    gru_kernel<<<grid, block, 0, stream>>>(x, w_ih, w_hh, b_ih, b_hh, out);
}